// Round 2
// baseline (2540.666 us; speedup 1.0000x reference)
//
#include <hip/hip_runtime.h>
#include <math.h>

#define B_ 64
#define L_ 512
#define C_ 256
#define H_ 4
#define LAY 3
#define NEGV -1e9f

#define BM 128
#define BN 128
#define BK 16
#define GEMM_ACC 1
#define GEMM_RELU 2

static __device__ __forceinline__ float sigmoidf_(float x) { return 1.f / (1.f + expf(-x)); }

// ---------------- mask / logical-position scan + pos_of_logical ----------------
__global__ void scan_kernel(const int* __restrict__ x, int* __restrict__ mask,
                            int* __restrict__ logical, int* __restrict__ pol,
                            int* __restrict__ nvalid) {
    int b = blockIdx.x, t = threadIdx.x;
    __shared__ int s[L_];
    int m = (x[b * L_ + t] != 0) ? 1 : 0;
    s[t] = m;
    __syncthreads();
    for (int off = 1; off < L_; off <<= 1) {
        int v = (t >= off) ? s[t - off] : 0;
        __syncthreads();
        s[t] += v;
        __syncthreads();
    }
    int cum = s[t];
    int lg = cum - 1; if (lg < 0) lg = 0;
    mask[b * L_ + t] = m;
    logical[b * L_ + t] = lg;
    if (m) pol[b * L_ + lg] = t;   // valid tokens have distinct logicals
    if (t == L_ - 1) nvalid[b] = cum;
}

// ---------------- h = (emb[x] + pos*mf)*mf ----------------
__global__ void embed_kernel(const int* __restrict__ x, const float* __restrict__ emb,
                             const float* __restrict__ pos, float* __restrict__ h) {
    int t = threadIdx.x;
    int bl = blockIdx.x * 4 + (t >> 6);
    int lane = t & 63;
    int xv = x[bl];
    float mf = (xv != 0) ? 1.f : 0.f;
    int l = bl & (L_ - 1);
    float4 e = *(const float4*)&emb[(size_t)xv * C_ + lane * 4];
    float4 p = *(const float4*)&pos[(size_t)l * C_ + lane * 4];
    float4 o;
    o.x = (e.x + p.x * mf) * mf;
    o.y = (e.y + p.y * mf) * mf;
    o.z = (e.z + p.z * mf) * mf;
    o.w = (e.w + p.w * mf) * mf;
    *(float4*)&h[(size_t)bl * C_ + lane * 4] = o;
}

// ---------------- fp32 GEMM: C[M,N] (ldc) = A[M,K] * B[N,K]^T (+bias, +acc, +relu) ----------------
__global__ __launch_bounds__(256) void sgemm_bt(const float* __restrict__ A,
                                                const float* __restrict__ Bw,
                                                float* __restrict__ Cm,
                                                const float* __restrict__ bias,
                                                int K, int ldc, int flags) {
    __shared__ float As[BK][BM + 4];
    __shared__ float Bs[BK][BN + 4];
    const int tid = threadIdx.x;
    const int tx = tid & 15, ty = tid >> 4;
    const float* Ab = A + (size_t)blockIdx.y * BM * K;
    const float* Bb = Bw + (size_t)blockIdx.x * BN * K;
    float acc[8][8];
#pragma unroll
    for (int i = 0; i < 8; i++)
#pragma unroll
        for (int j = 0; j < 8; j++) acc[i][j] = 0.f;

    for (int k0 = 0; k0 < K; k0 += BK) {
#pragma unroll
        for (int i = 0; i < 2; ++i) {
            int id = tid + i * 256;
            int row = id >> 2;
            int kq = (id & 3) << 2;
            float4 va = *(const float4*)(Ab + (size_t)row * K + k0 + kq);
            As[kq + 0][row] = va.x; As[kq + 1][row] = va.y;
            As[kq + 2][row] = va.z; As[kq + 3][row] = va.w;
            float4 vb = *(const float4*)(Bb + (size_t)row * K + k0 + kq);
            Bs[kq + 0][row] = vb.x; Bs[kq + 1][row] = vb.y;
            Bs[kq + 2][row] = vb.z; Bs[kq + 3][row] = vb.w;
        }
        __syncthreads();
#pragma unroll
        for (int k = 0; k < BK; ++k) {
            float a[8], b[8];
            *(float4*)&a[0] = *(const float4*)&As[k][ty * 8];
            *(float4*)&a[4] = *(const float4*)&As[k][ty * 8 + 4];
            *(float4*)&b[0] = *(const float4*)&Bs[k][tx * 8];
            *(float4*)&b[4] = *(const float4*)&Bs[k][tx * 8 + 4];
#pragma unroll
            for (int i = 0; i < 8; i++)
#pragma unroll
                for (int j = 0; j < 8; j++)
                    acc[i][j] = fmaf(a[i], b[j], acc[i][j]);
        }
        __syncthreads();
    }

    size_t rowbase = (size_t)blockIdx.y * BM + ty * 8;
    int colbase = blockIdx.x * BN + tx * 8;
#pragma unroll
    for (int i = 0; i < 8; i++) {
        float* crow = Cm + (rowbase + i) * (size_t)ldc + colbase;
#pragma unroll
        for (int j = 0; j < 8; j += 4) {
            float4 v;
            v.x = acc[i][j]; v.y = acc[i][j + 1]; v.z = acc[i][j + 2]; v.w = acc[i][j + 3];
            if (flags & GEMM_ACC) {
                float4 c0 = *(const float4*)&crow[j];
                v.x += c0.x; v.y += c0.y; v.z += c0.z; v.w += c0.w;
            }
            if (bias) {
                float4 bv = *(const float4*)&bias[colbase + j];
                v.x += bv.x; v.y += bv.y; v.z += bv.z; v.w += bv.w;
            }
            if (flags & GEMM_RELU) {
                v.x = fmaxf(v.x, 0.f); v.y = fmaxf(v.y, 0.f);
                v.z = fmaxf(v.z, 0.f); v.w = fmaxf(v.w, 0.f);
            }
            *(float4*)&crow[j] = v;
        }
    }
}

// ---------------- per-head attention scalars s,d (one direction) ----------------
__global__ void sd_kernel(const float* __restrict__ hp,
                          const float* __restrict__ a_s, const float* __restrict__ a_d,
                          float* __restrict__ s, float* __restrict__ d) {
    int bl = blockIdx.x;
    int t = threadIdx.x;
    int head = t >> 6, lane = t & 63;
    int b = bl >> 9, l = bl & 511;
    float vp = hp[(size_t)bl * C_ + head * 64 + lane];
    float s1 = vp * a_s[head * 64 + lane];
    float d1 = vp * a_d[head * 64 + lane];
#pragma unroll
    for (int off = 32; off; off >>= 1) {
        s1 += __shfl_down(s1, off);
        d1 += __shfl_down(d1, off);
    }
    if (lane == 0) {
        int idx = (b * H_ + head) * L_ + l;
        s[idx] = s1; d[idx] = d1;
    }
}

// ---------------- sparse GAT aggregation (one direction), writes m[B,L,512] half ----------------
__global__ void agg_kernel(const float* __restrict__ hp,
                           const float* __restrict__ s, const float* __restrict__ d,
                           const int* __restrict__ mask, const int* __restrict__ logical,
                           const int* __restrict__ pol, const int* __restrict__ nvalid,
                           float* __restrict__ m, int dil, int dir) {
    int bl = blockIdx.x;
    int c = threadIdx.x;
    int head = c >> 6;
    int b = bl >> 9, i = bl & 511;
    int mi = mask[bl];
    int li = logical[bl];
    int nv = nvalid[b];

    int js[3];
    int nn = 0;
    if (mi) {
#pragma unroll
        for (int k = 1; k <= 3; k++) {
            // dir 0 ("past" adj: diff<0 -> neighbor logical larger); dir 1: smaller
            int lj = dir ? (li - k * dil) : (li + k * dil);
            if (lj >= 0 && lj < nv) js[nn++] = pol[b * L_ + lj];
        }
    }
    int sidx = (b * H_ + head) * L_;
    float si = s[sidx + i];
    float e0 = si + d[sidx + i];
    e0 = e0 > 0.f ? e0 : 0.2f * e0;
    float ev[3];
    float emax = e0;
    for (int k = 0; k < nn; k++) {
        float e = si + d[sidx + js[k]];
        e = e > 0.f ? e : 0.2f * e;
        ev[k] = e;
        emax = fmaxf(emax, e);
    }
    float w0 = expf(e0 - emax);
    float den = w0;
    float wv[3];
    for (int k = 0; k < nn; k++) { wv[k] = expf(ev[k] - emax); den += wv[k]; }
    float outv = w0 * hp[(size_t)bl * C_ + c];
    for (int k = 0; k < nn; k++)
        outv += wv[k] * hp[((size_t)(b * L_ + js[k])) * C_ + c];
    m[(size_t)bl * (2 * C_) + dir * C_ + c] = outv / den;
}

// ---------------- GRU gates + LayerNorm + mask, h updated in place ----------------
__global__ void gate_ln_kernel(const float* __restrict__ G, const float* __restrict__ Hn,
                               float* __restrict__ h, const int* __restrict__ mask,
                               const float* __restrict__ lng, const float* __restrict__ lnb) {
    int bl = blockIdx.x;
    int c = threadIdx.x;
    __shared__ float red[8];
    size_t g0 = (size_t)bl * 768;
    float r = sigmoidf_(G[g0 + c]);          // ir+hr
    float z = sigmoidf_(G[g0 + 256 + c]);    // iz+hz
    float n = tanhf(G[g0 + 512 + c] + r * Hn[(size_t)bl * C_ + c]);
    float hv = h[(size_t)bl * C_ + c];
    float hn2 = (1.f - z) * n + z * hv;

    int lane = c & 63, wave = c >> 6;
    float sum = hn2;
#pragma unroll
    for (int off = 32; off; off >>= 1) sum += __shfl_down(sum, off);
    if (lane == 0) red[wave] = sum;
    __syncthreads();
    float mu = (red[0] + red[1] + red[2] + red[3]) * (1.f / 256.f);
    float dv = hn2 - mu;
    float sq = dv * dv;
#pragma unroll
    for (int off = 32; off; off >>= 1) sq += __shfl_down(sq, off);
    __syncthreads();
    if (lane == 0) red[wave] = sq;
    __syncthreads();
    float var = (red[0] + red[1] + red[2] + red[3]) * (1.f / 256.f);
    float y = dv * rsqrtf(var + 1e-5f) * lng[c] + lnb[c];
    h[(size_t)bl * C_ + c] = mask[bl] ? y : 0.f;
}

// ---------------- masked softmax pooling + both heads ----------------
__global__ __launch_bounds__(256) void pool_head_kernel(
    const float* __restrict__ h, const int* __restrict__ mask,
    const float* __restrict__ pw, const float* __restrict__ pb,
    const float* __restrict__ h0W, const float* __restrict__ h0b,
    const float* __restrict__ h1W, const float* __restrict__ h1b,
    float* __restrict__ out) {
    int b = blockIdx.x;
    int t = threadIdx.x;
    int lane = t & 63, wave = t >> 6;
    __shared__ float sc[L_];
    __shared__ float red[8];
    __shared__ float pooled[C_];
    float4 wv = *(const float4*)&pw[lane * 4];
    for (int l = wave; l < L_; l += 4) {
        float4 hv = *(const float4*)&h[((size_t)b * L_ + l) * C_ + lane * 4];
        float p = hv.x * wv.x + hv.y * wv.y + hv.z * wv.z + hv.w * wv.w;
#pragma unroll
        for (int off = 32; off; off >>= 1) p += __shfl_down(p, off);
        if (lane == 0) sc[l] = mask[b * L_ + l] ? (p + pb[0]) : NEGV;
    }
    __syncthreads();
    float v1 = sc[t], v2 = sc[t + 256];
    float mx = fmaxf(v1, v2);
#pragma unroll
    for (int off = 32; off; off >>= 1) mx = fmaxf(mx, __shfl_down(mx, off));
    if (lane == 0) red[wave] = mx;
    __syncthreads();
    float gmax = fmaxf(fmaxf(red[0], red[1]), fmaxf(red[2], red[3]));
    float e1 = expf(v1 - gmax), e2 = expf(v2 - gmax);
    float ss = e1 + e2;
#pragma unroll
    for (int off = 32; off; off >>= 1) ss += __shfl_down(ss, off);
    if (lane == 0) red[wave + 4] = ss;
    __syncthreads();
    float gsum = red[4] + red[5] + red[6] + red[7];
    float inv = 1.f / gsum;
    sc[t] = e1 * inv;
    sc[t + 256] = e2 * inv;
    __syncthreads();
    float acc = 0.f;
    for (int l = 0; l < L_; l++)
        acc = fmaf(sc[l], h[((size_t)b * L_ + l) * C_ + t], acc);
    pooled[t] = acc;
    __syncthreads();
    if (t < 70) {
        const float* W;
        float bb;
        if (t < 50) { W = h0W + (size_t)t * C_; bb = h0b[t]; }
        else        { W = h1W + (size_t)(t - 50) * C_; bb = h1b[t - 50]; }
        float o = bb;
        for (int c2 = 0; c2 < C_; c2++) o = fmaf(pooled[c2], W[c2], o);
        out[b * 70 + t] = o;
    }
}

extern "C" void kernel_launch(void* const* d_in, const int* in_sizes, int n_in,
                              void* d_out, int out_size, void* d_ws, size_t ws_size,
                              hipStream_t stream) {
    const int*   x    = (const int*)d_in[0];
    const float* emb  = (const float*)d_in[1];
    const float* pos  = (const float*)d_in[2];
    const float* gpW  = (const float*)d_in[3];
    const float* gpas = (const float*)d_in[4];
    const float* gpad = (const float*)d_in[5];
    const float* gfW  = (const float*)d_in[6];
    const float* gfas = (const float*)d_in[7];
    const float* gfad = (const float*)d_in[8];
    const float* msgW = (const float*)d_in[9];
    const float* msgb = (const float*)d_in[10];
    const float* Wih  = (const float*)d_in[11];
    const float* bih  = (const float*)d_in[12];
    const float* Whh  = (const float*)d_in[13];
    const float* bhh  = (const float*)d_in[14];
    const float* lng  = (const float*)d_in[15];
    const float* lnb  = (const float*)d_in[16];
    const float* pw   = (const float*)d_in[17];
    const float* pb   = (const float*)d_in[18];
    const float* h0W  = (const float*)d_in[19];
    const float* h0b  = (const float*)d_in[20];
    const float* h1W  = (const float*)d_in[21];
    const float* h1b  = (const float*)d_in[22];
    float* out = (float*)d_out;

    const size_t BLC = (size_t)B_ * L_ * C_;   // 8,388,608 floats = 32 MiB
    const size_t BHL = (size_t)B_ * H_ * L_;
    // Workspace layout (BLC slots), total 5*BLC*4B = 160 MiB + ~1.3 MiB extras:
    //   slot0: h (persistent)
    //   slot1: hp (per-direction GAT projection) -> mm (msg out) -> Hn
    //   slot2-3: m [B,L,512]  (dead once mm computed)
    //   slot2-4: G [B,L,768]  (aliases m + slot4; written after m is dead)
    float* ws = (float*)d_ws;
    float* h  = ws;
    float* hp = ws + BLC;            // also mm, Hn
    float* m  = ws + 2 * BLC;        // [B,L,512]
    float* G  = ws + 2 * BLC;        // [B,L,768], overlaps m (intentional)
    float* sp = ws + 5 * BLC;        // [B,H,L]
    float* dp = sp + BHL;
    int* mask    = (int*)(dp + BHL);
    int* logical = mask + B_ * L_;
    int* pol     = logical + B_ * L_;
    int* nvalid  = pol + B_ * L_;
    // total = 5*BLC*4 + 2*BHL*4 + (3*B*L+B)*4  ~= 162 MiB  (fits 256 MiB ws)

    scan_kernel<<<B_, L_, 0, stream>>>(x, mask, logical, pol, nvalid);
    embed_kernel<<<B_ * L_ / 4, 256, 0, stream>>>(x, emb, pos, h);

    const int DILS[LAY] = {1, 2, 4};
    const dim3 g256(C_ / BN, B_ * L_ / BM);
    const dim3 g512(512 / BN, B_ * L_ / BM);
    const dim3 g768(768 / BN, B_ * L_ / BM);

    for (int l = 0; l < LAY; l++) {
        const float* WP  = gpW + (size_t)l * C_ * C_;
        const float* WF  = gfW + (size_t)l * C_ * C_;
        const float* WM  = msgW + (size_t)l * C_ * 2 * C_;
        const float* WIH = Wih + (size_t)l * 768 * C_;
        const float* WHH = Whh + (size_t)l * 768 * C_;
        int dil = DILS[l];

        // --- past direction ---
        sgemm_bt<<<g256, 256, 0, stream>>>(h, WP, hp, nullptr, C_, C_, 0);
        sd_kernel<<<B_ * L_, 256, 0, stream>>>(hp, gpas + l * C_, gpad + l * C_, sp, dp);
        agg_kernel<<<B_ * L_, 256, 0, stream>>>(hp, sp, dp, mask, logical, pol, nvalid,
                                                m, dil, 0);
        // --- future direction (hp reused) ---
        sgemm_bt<<<g256, 256, 0, stream>>>(h, WF, hp, nullptr, C_, C_, 0);
        sd_kernel<<<B_ * L_, 256, 0, stream>>>(hp, gfas + l * C_, gfad + l * C_, sp, dp);
        agg_kernel<<<B_ * L_, 256, 0, stream>>>(hp, sp, dp, mask, logical, pol, nvalid,
                                                m, dil, 1);
        // mm = relu(m @ msg_W^T + msg_b)   (mm aliases hp; reads slots2-3, writes slot1)
        sgemm_bt<<<g256, 256, 0, stream>>>(m, WM, hp, msgb + l * C_, 2 * C_, C_, GEMM_RELU);
        // G = mm @ Wih^T + bih             (reads slot1, writes slots2-4; m is dead)
        sgemm_bt<<<g768, 256, 0, stream>>>(hp, WIH, G, bih + l * 768, C_, 768, 0);
        // G[:, :512] += h @ Whh[:512]^T + bhh[:512]
        sgemm_bt<<<g512, 256, 0, stream>>>(h, WHH, G, bhh + l * 768, C_, 768, GEMM_ACC);
        // Hn = h @ Whh[512:]^T + bhh[512:] (Hn aliases hp; mm dead now)
        sgemm_bt<<<g256, 256, 0, stream>>>(h, WHH + 512 * C_, hp, bhh + l * 768 + 512,
                                           C_, C_, 0);
        gate_ln_kernel<<<B_ * L_, 256, 0, stream>>>(G, hp, h, mask,
                                                    lng + l * C_, lnb + l * C_);
    }

    pool_head_kernel<<<B_, 256, 0, stream>>>(h, mask, pw, pb, h0W, h0b, h1W, h1b, out);
}

// Round 3
// 1282.188 us; speedup vs baseline: 1.9815x; 1.9815x over previous
//
#include <hip/hip_runtime.h>
#include <math.h>

#define B_ 64
#define L_ 512
#define C_ 256
#define H_ 4
#define LAY 3
#define NEGV -1e9f

#define GF_BIAS  1
#define GF_RELU  2
#define GF_OBF16 4
#define GF_SPLIT 8

typedef __attribute__((ext_vector_type(8))) short short8;
typedef __attribute__((ext_vector_type(4))) float floatx4;

static __device__ __forceinline__ float sigmoidf_(float x) { return 1.f / (1.f + expf(-x)); }

static __device__ __forceinline__ short f2bf(float f) {
    unsigned x = __float_as_uint(f);
    x += 0x7fffu + ((x >> 16) & 1u);       // round-to-nearest-even to bf16
    return (short)(x >> 16);
}

static __device__ __forceinline__ void gl_lds16(const short* g, short* l) {
    __builtin_amdgcn_global_load_lds(
        (const __attribute__((address_space(1))) unsigned int*)g,
        (__attribute__((address_space(3))) unsigned int*)l, 16, 0, 0);
}

// ---------------- mask / logical-position scan + pos_of_logical ----------------
__global__ void scan_kernel(const int* __restrict__ x, int* __restrict__ mask,
                            int* __restrict__ logical, int* __restrict__ pol,
                            int* __restrict__ nvalid) {
    int b = blockIdx.x, t = threadIdx.x;
    __shared__ int s[L_];
    int m = (x[b * L_ + t] != 0) ? 1 : 0;
    s[t] = m;
    __syncthreads();
    for (int off = 1; off < L_; off <<= 1) {
        int v = (t >= off) ? s[t - off] : 0;
        __syncthreads();
        s[t] += v;
        __syncthreads();
    }
    int cum = s[t];
    int lg = cum - 1; if (lg < 0) lg = 0;
    mask[b * L_ + t] = m;
    logical[b * L_ + t] = lg;
    if (m) pol[b * L_ + lg] = t;
    if (t == L_ - 1) nvalid[b] = cum;
}

// ---------------- h = (emb[x] + pos*mf)*mf  (fp32 + bf16 copies) ----------------
__global__ void embed_kernel(const int* __restrict__ x, const float* __restrict__ emb,
                             const float* __restrict__ pos, float* __restrict__ h,
                             short* __restrict__ hb) {
    int t = threadIdx.x;
    int bl = blockIdx.x * 4 + (t >> 6);
    int lane = t & 63;
    int xv = x[bl];
    float mf = (xv != 0) ? 1.f : 0.f;
    int l = bl & (L_ - 1);
    float4 e = *(const float4*)&emb[(size_t)xv * C_ + lane * 4];
    float4 p = *(const float4*)&pos[(size_t)l * C_ + lane * 4];
    float4 o;
    o.x = (e.x + p.x * mf) * mf;
    o.y = (e.y + p.y * mf) * mf;
    o.z = (e.z + p.z * mf) * mf;
    o.w = (e.w + p.w * mf) * mf;
    *(float4*)&h[(size_t)bl * C_ + lane * 4] = o;
    size_t hb0 = (size_t)bl * C_ + lane * 4;
    hb[hb0 + 0] = f2bf(o.x); hb[hb0 + 1] = f2bf(o.y);
    hb[hb0 + 2] = f2bf(o.z); hb[hb0 + 3] = f2bf(o.w);
}

// ---------------- fp32 -> bf16 weight conversion ----------------
__global__ void f2bf_kernel(const float* __restrict__ s, short* __restrict__ d, int n) {
    int i = blockIdx.x * 256 + threadIdx.x;
    if (i < n) d[i] = f2bf(s[i]);
}

// ---------------- bf16 MFMA GEMM: C[M,N] = A[M,K] * B[N,K]^T ----------------
// 128x128 tile, 4 waves in 2x2, each wave 64x64 via 4x4 mfma_f32_16x16x32_bf16.
// Staging via global_load_lds width=16 (LDS dest = base + lane*16, contiguous).
__global__ __launch_bounds__(256) void bgemm(const short* __restrict__ A,
                                             const short* __restrict__ Bw,
                                             float* __restrict__ Cf,
                                             float* __restrict__ Cs,
                                             const float* __restrict__ bias,
                                             int K, int ldc, int flags) {
    __shared__ short As[128 * 32];
    __shared__ short Bs[128 * 32];
    const int tid = threadIdx.x;
    const int wave = tid >> 6, lane = tid & 63;
    const int wm = wave >> 1, wn = wave & 1;
    const short* Ab = A + (size_t)blockIdx.y * 128 * K;
    const short* Bb = Bw + (size_t)blockIdx.x * 128 * K;
    floatx4 acc[4][4];
#pragma unroll
    for (int i = 0; i < 4; i++)
#pragma unroll
        for (int j = 0; j < 4; j++) acc[i][j] = (floatx4)0.f;

    const int srow = lane >> 2;            // 0..15
    const int sq = (lane & 3) * 8;         // 16B chunk within 64B row
    const int q = lane >> 4, t16 = lane & 15;

    for (int k0 = 0; k0 < K; k0 += 32) {
#pragma unroll
        for (int t = 0; t < 2; ++t) {
            int r = (wave * 2 + t) * 16 + srow;
            gl_lds16(Ab + (size_t)r * K + k0 + sq, &As[r * 32 + sq]);
            gl_lds16(Bb + (size_t)r * K + k0 + sq, &Bs[r * 32 + sq]);
        }
        __syncthreads();
        short8 af[4], bfr[4];
#pragma unroll
        for (int mf = 0; mf < 4; mf++)
            af[mf] = *(const short8*)&As[(wm * 64 + mf * 16 + t16) * 32 + q * 8];
#pragma unroll
        for (int nf = 0; nf < 4; nf++)
            bfr[nf] = *(const short8*)&Bs[(wn * 64 + nf * 16 + t16) * 32 + q * 8];
#pragma unroll
        for (int mf = 0; mf < 4; mf++)
#pragma unroll
            for (int nf = 0; nf < 4; nf++)
                acc[mf][nf] = __builtin_amdgcn_mfma_f32_16x16x32_bf16(
                    af[mf], bfr[nf], acc[mf][nf], 0, 0, 0);
        __syncthreads();
    }

    const int rowbase = blockIdx.y * 128 + wm * 64;
    const int colbase = blockIdx.x * 128 + wn * 64;
#pragma unroll
    for (int nf = 0; nf < 4; nf++) {
        int col = colbase + nf * 16 + t16;
        float bv = (flags & GF_BIAS) ? bias[col] : 0.f;
#pragma unroll
        for (int mf = 0; mf < 4; mf++) {
            int row0 = rowbase + mf * 16 + q * 4;
#pragma unroll
            for (int r = 0; r < 4; r++) {
                float v = acc[mf][nf][r] + bv;
                if (flags & GF_RELU) v = fmaxf(v, 0.f);
                size_t row = (size_t)(row0 + r);
                if (flags & GF_SPLIT) {
                    if (col < 512) Cf[row * 768 + col] += v;       // G accumulate (r,z)
                    else           Cs[row * 256 + (col - 512)] = v; // Hn
                } else if (flags & GF_OBF16) {
                    ((short*)Cf)[row * ldc + col] = f2bf(v);
                } else {
                    Cf[row * ldc + col] = v;
                }
            }
        }
    }
}

// ---------------- fused GAT scores + sparse aggregation (one direction) ----------------
__global__ void agg_fused(const float* __restrict__ hp,
                          const float* __restrict__ a_s, const float* __restrict__ a_d,
                          const int* __restrict__ mask, const int* __restrict__ logical,
                          const int* __restrict__ pol, const int* __restrict__ nvalid,
                          short* __restrict__ m, int dil, int dir) {
    int bl = blockIdx.x;
    int c = threadIdx.x;               // channel 0..255; head = c>>6; lane-in-head = c&63
    int b = bl >> 9;
    int mi = mask[bl];
    int li = logical[bl];
    int nv = nvalid[b];
    int js[3]; int nn = 0;
    if (mi) {
#pragma unroll
        for (int k = 1; k <= 3; k++) {
            int lj = dir ? (li - k * dil) : (li + k * dil);
            if (lj >= 0 && lj < nv) js[nn++] = pol[b * L_ + lj];
        }
    }
    float asv = a_s[c], adv = a_d[c];
    float vs = hp[(size_t)bl * C_ + c];
    float vj[3];
    for (int k = 0; k < nn; k++) vj[k] = hp[((size_t)(b * L_ + js[k])) * C_ + c];

    float ss = vs * asv, ds = vs * adv;
#pragma unroll
    for (int off = 32; off; off >>= 1) { ss += __shfl_xor(ss, off); ds += __shfl_xor(ds, off); }
    float dj[3];
    for (int k = 0; k < nn; k++) {
        float dv = vj[k] * adv;
#pragma unroll
        for (int off = 32; off; off >>= 1) dv += __shfl_xor(dv, off);
        dj[k] = dv;
    }
    float e0 = ss + ds; e0 = e0 > 0.f ? e0 : 0.2f * e0;
    float emax = e0, ev[3];
    for (int k = 0; k < nn; k++) {
        float e = ss + dj[k]; e = e > 0.f ? e : 0.2f * e;
        ev[k] = e; emax = fmaxf(emax, e);
    }
    float w0 = expf(e0 - emax), den = w0;
    float wv[3];
    for (int k = 0; k < nn; k++) { wv[k] = expf(ev[k] - emax); den += wv[k]; }
    float out = w0 * vs;
    for (int k = 0; k < nn; k++) out += wv[k] * vj[k];
    m[(size_t)bl * 512 + dir * 256 + c] = f2bf(out / den);
}

// ---------------- GRU gates + LayerNorm + mask; h fp32 + bf16 updated ----------------
__global__ void gate_ln_kernel(const float* __restrict__ G, const float* __restrict__ Hn,
                               float* __restrict__ h, short* __restrict__ hb,
                               const int* __restrict__ mask,
                               const float* __restrict__ lng, const float* __restrict__ lnb) {
    int bl = blockIdx.x;
    int c = threadIdx.x;
    __shared__ float red[8];
    size_t g0 = (size_t)bl * 768;
    float r = sigmoidf_(G[g0 + c]);
    float z = sigmoidf_(G[g0 + 256 + c]);
    float n = tanhf(G[g0 + 512 + c] + r * Hn[(size_t)bl * C_ + c]);
    float hv = h[(size_t)bl * C_ + c];
    float hn2 = (1.f - z) * n + z * hv;

    int lane = c & 63, wave = c >> 6;
    float sum = hn2;
#pragma unroll
    for (int off = 32; off; off >>= 1) sum += __shfl_down(sum, off);
    if (lane == 0) red[wave] = sum;
    __syncthreads();
    float mu = (red[0] + red[1] + red[2] + red[3]) * (1.f / 256.f);
    float dv = hn2 - mu;
    float sq = dv * dv;
#pragma unroll
    for (int off = 32; off; off >>= 1) sq += __shfl_down(sq, off);
    __syncthreads();
    if (lane == 0) red[wave] = sq;
    __syncthreads();
    float var = (red[0] + red[1] + red[2] + red[3]) * (1.f / 256.f);
    float y = dv * rsqrtf(var + 1e-5f) * lng[c] + lnb[c];
    float outv = mask[bl] ? y : 0.f;
    h[(size_t)bl * C_ + c] = outv;
    hb[(size_t)bl * C_ + c] = f2bf(outv);
}

// ---------------- masked softmax pooling + both heads ----------------
__global__ __launch_bounds__(256) void pool_head_kernel(
    const float* __restrict__ h, const int* __restrict__ mask,
    const float* __restrict__ pw, const float* __restrict__ pb,
    const float* __restrict__ h0W, const float* __restrict__ h0b,
    const float* __restrict__ h1W, const float* __restrict__ h1b,
    float* __restrict__ out) {
    int b = blockIdx.x;
    int t = threadIdx.x;
    int lane = t & 63, wave = t >> 6;
    __shared__ float sc[L_];
    __shared__ float red[8];
    __shared__ float pooled[C_];
    float4 wv = *(const float4*)&pw[lane * 4];
    for (int l = wave; l < L_; l += 4) {
        float4 hv = *(const float4*)&h[((size_t)b * L_ + l) * C_ + lane * 4];
        float p = hv.x * wv.x + hv.y * wv.y + hv.z * wv.z + hv.w * wv.w;
#pragma unroll
        for (int off = 32; off; off >>= 1) p += __shfl_down(p, off);
        if (lane == 0) sc[l] = mask[b * L_ + l] ? (p + pb[0]) : NEGV;
    }
    __syncthreads();
    float v1 = sc[t], v2 = sc[t + 256];
    float mx = fmaxf(v1, v2);
#pragma unroll
    for (int off = 32; off; off >>= 1) mx = fmaxf(mx, __shfl_down(mx, off));
    if (lane == 0) red[wave] = mx;
    __syncthreads();
    float gmax = fmaxf(fmaxf(red[0], red[1]), fmaxf(red[2], red[3]));
    float e1 = expf(v1 - gmax), e2 = expf(v2 - gmax);
    float ss = e1 + e2;
#pragma unroll
    for (int off = 32; off; off >>= 1) ss += __shfl_down(ss, off);
    if (lane == 0) red[wave + 4] = ss;
    __syncthreads();
    float gsum = red[4] + red[5] + red[6] + red[7];
    float inv = 1.f / gsum;
    sc[t] = e1 * inv;
    sc[t + 256] = e2 * inv;
    __syncthreads();
    float acc = 0.f;
    for (int l = 0; l < L_; l++)
        acc = fmaf(sc[l], h[((size_t)b * L_ + l) * C_ + t], acc);
    pooled[t] = acc;
    __syncthreads();
    if (t < 70) {
        const float* W;
        float bb;
        if (t < 50) { W = h0W + (size_t)t * C_; bb = h0b[t]; }
        else        { W = h1W + (size_t)(t - 50) * C_; bb = h1b[t - 50]; }
        float o = bb;
        for (int c2 = 0; c2 < C_; c2++) o = fmaf(pooled[c2], W[c2], o);
        out[b * 70 + t] = o;
    }
}

extern "C" void kernel_launch(void* const* d_in, const int* in_sizes, int n_in,
                              void* d_out, int out_size, void* d_ws, size_t ws_size,
                              hipStream_t stream) {
    const int*   x    = (const int*)d_in[0];
    const float* emb  = (const float*)d_in[1];
    const float* pos  = (const float*)d_in[2];
    const float* gpW  = (const float*)d_in[3];
    const float* gpas = (const float*)d_in[4];
    const float* gpad = (const float*)d_in[5];
    const float* gfW  = (const float*)d_in[6];
    const float* gfas = (const float*)d_in[7];
    const float* gfad = (const float*)d_in[8];
    const float* msgW = (const float*)d_in[9];
    const float* msgb = (const float*)d_in[10];
    const float* Wih  = (const float*)d_in[11];
    const float* bih  = (const float*)d_in[12];
    const float* Whh  = (const float*)d_in[13];
    const float* bhh  = (const float*)d_in[14];
    const float* lng  = (const float*)d_in[15];
    const float* lnb  = (const float*)d_in[16];
    const float* pw   = (const float*)d_in[17];
    const float* pb   = (const float*)d_in[18];
    const float* h0W  = (const float*)d_in[19];
    const float* h0b  = (const float*)d_in[20];
    const float* h1W  = (const float*)d_in[21];
    const float* h1b  = (const float*)d_in[22];
    float* out = (float*)d_out;

    // Workspace layout (units: floats; MW = 1Mi floats = 4MiB). Total ~228.5 MiB.
    const size_t MW = 1024 * 1024;
    float* ws = (float*)d_ws;
    float* h   = ws;                          // [0,8M)   h fp32
    short* hb  = (short*)(ws + 8 * MW);       // [8M,12M) h bf16
    short* mmb = (short*)(ws + 12 * MW);      // [12M,16M) msg-out bf16
    float* hp  = ws + 16 * MW;                // [16M,24M) GAT proj fp32; later Hn fp32
    short* mb  = (short*)(ws + 24 * MW);      // [24M,32M) m [32768,512] bf16
    float* G   = ws + 32 * MW;                // [32M,56M) G [32768,768] fp32
    short* wb  = (short*)(ws + 56 * MW);      // bf16 weights (~3.75 MiB)
    short* gpWb  = wb;                        // 3*65536
    short* gfWb  = gpWb + 3 * 65536;
    short* msgWb = gfWb + 3 * 65536;          // 3*131072
    short* WihWb = msgWb + 3 * 131072;        // 3*196608
    short* WhhWb = WihWb + 3 * 196608;        // 3*196608
    int* mask    = (int*)(ws + 57 * MW);
    int* logical = mask + B_ * L_;
    int* pol     = logical + B_ * L_;
    int* nvalid  = pol + B_ * L_;

    // weight conversions (per call; inputs restored every call)
    f2bf_kernel<<<(3 * 65536 + 255) / 256, 256, 0, stream>>>(gpW, gpWb, 3 * 65536);
    f2bf_kernel<<<(3 * 65536 + 255) / 256, 256, 0, stream>>>(gfW, gfWb, 3 * 65536);
    f2bf_kernel<<<(3 * 131072 + 255) / 256, 256, 0, stream>>>(msgW, msgWb, 3 * 131072);
    f2bf_kernel<<<(3 * 196608 + 255) / 256, 256, 0, stream>>>(Wih, WihWb, 3 * 196608);
    f2bf_kernel<<<(3 * 196608 + 255) / 256, 256, 0, stream>>>(Whh, WhhWb, 3 * 196608);

    scan_kernel<<<B_, L_, 0, stream>>>(x, mask, logical, pol, nvalid);
    embed_kernel<<<B_ * L_ / 4, 256, 0, stream>>>(x, emb, pos, h, hb);

    const int DILS[LAY] = {1, 2, 4};
    const dim3 gN256(2, 256), gN768(6, 256);

    for (int l = 0; l < LAY; l++) {
        int dil = DILS[l];
        // past direction
        bgemm<<<gN256, 256, 0, stream>>>(hb, gpWb + l * 65536, hp, nullptr, nullptr,
                                         256, 256, 0);
        agg_fused<<<B_ * L_, 256, 0, stream>>>(hp, gpas + l * C_, gpad + l * C_,
                                               mask, logical, pol, nvalid, mb, dil, 0);
        // future direction
        bgemm<<<gN256, 256, 0, stream>>>(hb, gfWb + l * 65536, hp, nullptr, nullptr,
                                         256, 256, 0);
        agg_fused<<<B_ * L_, 256, 0, stream>>>(hp, gfas + l * C_, gfad + l * C_,
                                               mask, logical, pol, nvalid, mb, dil, 1);
        // mm = relu(m @ msgW^T + msgb)  -> bf16
        bgemm<<<gN256, 256, 0, stream>>>(mb, msgWb + l * 131072, (float*)mmb, nullptr,
                                         msgb + l * C_, 512, 256,
                                         GF_BIAS | GF_RELU | GF_OBF16);
        // G = mm @ Wih^T + bih   (fp32, ldc 768)
        bgemm<<<gN768, 256, 0, stream>>>(mmb, WihWb + l * 196608, G, nullptr,
                                         bih + l * 768, 256, 768, GF_BIAS);
        // split: G[:, :512] += h@Whh[:512]^T + bhh[:512]; Hn = h@Whh[512:]^T + bhh[512:]
        bgemm<<<gN768, 256, 0, stream>>>(hb, WhhWb + l * 196608, G, hp,
                                         bhh + l * 768, 256, 768, GF_BIAS | GF_SPLIT);
        gate_ln_kernel<<<B_ * L_, 256, 0, stream>>>(G, hp, h, hb, mask,
                                                    lng + l * C_, lnb + l * C_);
    }

    pool_head_kernel<<<B_, 256, 0, stream>>>(h, mask, pw, pb, h0W, h0b, h1W, h1b, out);
}

// Round 5
// 1071.606 us; speedup vs baseline: 2.3709x; 1.1965x over previous
//
#include <hip/hip_runtime.h>
#include <math.h>

#define B_ 64
#define L_ 512
#define C_ 256
#define H_ 4
#define LAY 3
#define NEGV -1e9f

#define GF_BIAS  1
#define GF_RELU  2
#define GF_OBF16 4

typedef __attribute__((ext_vector_type(8))) short short8;
typedef __attribute__((ext_vector_type(4))) float floatx4;

static __device__ __forceinline__ float sigmoidf_(float x) { return 1.f / (1.f + expf(-x)); }

static __device__ __forceinline__ short f2bf(float f) {
    unsigned x = __float_as_uint(f);
    x += 0x7fffu + ((x >> 16) & 1u);       // round-to-nearest-even to bf16
    return (short)(x >> 16);
}
static __device__ __forceinline__ float bf2f(short s) {
    return __uint_as_float(((unsigned)(unsigned short)s) << 16);
}

static __device__ __forceinline__ void gl_lds16(const short* g, short* l) {
    __builtin_amdgcn_global_load_lds(
        (const __attribute__((address_space(1))) unsigned int*)g,
        (__attribute__((address_space(3))) unsigned int*)l, 16, 0, 0);
}

// ---------------- mask / logical-position scan + pos_of_logical ----------------
__global__ void scan_kernel(const int* __restrict__ x, int* __restrict__ mask,
                            int* __restrict__ logical, int* __restrict__ pol,
                            int* __restrict__ nvalid) {
    int b = blockIdx.x, t = threadIdx.x;
    __shared__ int s[L_];
    int m = (x[b * L_ + t] != 0) ? 1 : 0;
    s[t] = m;
    __syncthreads();
    for (int off = 1; off < L_; off <<= 1) {
        int v = (t >= off) ? s[t - off] : 0;
        __syncthreads();
        s[t] += v;
        __syncthreads();
    }
    int cum = s[t];
    int lg = cum - 1; if (lg < 0) lg = 0;
    mask[b * L_ + t] = m;
    logical[b * L_ + t] = lg;
    if (m) pol[b * L_ + lg] = t;
    if (t == L_ - 1) nvalid[b] = cum;
}

// ---------------- h = (emb[x] + pos*mf)*mf  (fp32 + bf16 copies) ----------------
__global__ void embed_kernel(const int* __restrict__ x, const float* __restrict__ emb,
                             const float* __restrict__ pos, float* __restrict__ h,
                             short* __restrict__ hb) {
    int t = threadIdx.x;
    int bl = blockIdx.x * 4 + (t >> 6);
    int lane = t & 63;
    int xv = x[bl];
    float mf = (xv != 0) ? 1.f : 0.f;
    int l = bl & (L_ - 1);
    float4 e = *(const float4*)&emb[(size_t)xv * C_ + lane * 4];
    float4 p = *(const float4*)&pos[(size_t)l * C_ + lane * 4];
    float4 o;
    o.x = (e.x + p.x * mf) * mf;
    o.y = (e.y + p.y * mf) * mf;
    o.z = (e.z + p.z * mf) * mf;
    o.w = (e.w + p.w * mf) * mf;
    *(float4*)&h[(size_t)bl * C_ + lane * 4] = o;
    size_t hb0 = (size_t)bl * C_ + lane * 4;
    hb[hb0 + 0] = f2bf(o.x); hb[hb0 + 1] = f2bf(o.y);
    hb[hb0 + 2] = f2bf(o.z); hb[hb0 + 3] = f2bf(o.w);
}

// ---------------- weight prep ----------------
__global__ void f2bf_kernel(const float* __restrict__ s, short* __restrict__ d, int n) {
    int i = blockIdx.x * 256 + threadIdx.x;
    if (i < n) d[i] = f2bf(s[i]);
}

// W2cat[l][512][256]: rows 0..255 = gpW[l], 256..511 = gfW[l]
__global__ void prep_w2(const float* __restrict__ gpW, const float* __restrict__ gfW,
                        short* __restrict__ W2) {
    int i = blockIdx.x * 256 + threadIdx.x;
    if (i >= 3 * 512 * 256) return;
    int k = i & 255, r = (i >> 8) & 511, l = i >> 17;
    float v = (r < 256) ? gpW[((size_t)l * 256 + r) * 256 + k]
                        : gfW[((size_t)l * 256 + (r - 256)) * 256 + k];
    W2[i] = f2bf(v);
}

// Bcat[l][1024][512]: rows 0..511: [Wih[g] | Whh[g]]; 512..767: [Wih[g] | 0]; 768..1023: [0 | Whh[g-256]]
__global__ void prep_gru(const float* __restrict__ Wih, const float* __restrict__ Whh,
                         short* __restrict__ Bc) {
    int i = blockIdx.x * 256 + threadIdx.x;
    if (i >= 3 * 1024 * 512) return;
    int k = i & 511, r = (i >> 9) & 1023, l = i >> 19;
    float v;
    if (r < 512)      v = (k < 256) ? Wih[((size_t)l * 768 + r) * 256 + k]
                                    : Whh[((size_t)l * 768 + r) * 256 + (k - 256)];
    else if (r < 768) v = (k < 256) ? Wih[((size_t)l * 768 + r) * 256 + k] : 0.f;
    else              v = (k >= 256) ? Whh[((size_t)l * 768 + (r - 256)) * 256 + (k - 256)] : 0.f;
    Bc[i] = f2bf(v);
}

__global__ void prep_bias(const float* __restrict__ bih, const float* __restrict__ bhh,
                          float* __restrict__ bc) {
    int i = blockIdx.x * 256 + threadIdx.x;
    if (i >= 3 * 1024) return;
    int c = i & 1023, l = i >> 10;
    float v;
    if (c < 512)      v = bih[l * 768 + c] + bhh[l * 768 + c];
    else if (c < 768) v = bih[l * 768 + c];
    else              v = bhh[l * 768 + (c - 256)];
    bc[i] = v;
}

// ---------------- bf16 MFMA GEMM: C[M,N] = A[M,K] * B[N,K]^T ----------------
// A optionally split at k=256 between A0 (stride lda) and A1 (stride 256).
__global__ __launch_bounds__(256) void bgemm(const short* __restrict__ A0,
                                             const short* __restrict__ A1,
                                             const short* __restrict__ Bw,
                                             void* __restrict__ Cout,
                                             const float* __restrict__ bias,
                                             int K, int lda, int ldc, int flags) {
    __shared__ short As[128 * 32];
    __shared__ short Bs[128 * 32];
    const int tid = threadIdx.x;
    const int wave = tid >> 6, lane = tid & 63;
    const int wm = wave >> 1, wn = wave & 1;
    const size_t arow0 = (size_t)blockIdx.y * 128;
    const short* Bb = Bw + (size_t)blockIdx.x * 128 * K;
    floatx4 acc[4][4];
#pragma unroll
    for (int i = 0; i < 4; i++)
#pragma unroll
        for (int j = 0; j < 4; j++) acc[i][j] = (floatx4)0.f;

    const int srow = lane >> 2;            // 0..15
    const int sq = (lane & 3) * 8;         // 16B chunk within 64B row
    const int q = lane >> 4, t16 = lane & 15;

    for (int k0 = 0; k0 < K; k0 += 32) {
        bool useA1 = (A1 != nullptr) && (k0 >= 256);
        const short* Abase = useA1 ? (A1 + arow0 * 256 + (k0 - 256))
                                   : (A0 + arow0 * (size_t)lda + k0);
        int astr = useA1 ? 256 : lda;
#pragma unroll
        for (int t = 0; t < 2; ++t) {
            int r = (wave * 2 + t) * 16 + srow;
            gl_lds16(Abase + (size_t)r * astr + sq, &As[r * 32 + sq]);
            gl_lds16(Bb + (size_t)r * K + k0 + sq, &Bs[r * 32 + sq]);
        }
        __syncthreads();
        short8 af[4], bfr[4];
#pragma unroll
        for (int mf = 0; mf < 4; mf++)
            af[mf] = *(const short8*)&As[(wm * 64 + mf * 16 + t16) * 32 + q * 8];
#pragma unroll
        for (int nf = 0; nf < 4; nf++)
            bfr[nf] = *(const short8*)&Bs[(wn * 64 + nf * 16 + t16) * 32 + q * 8];
#pragma unroll
        for (int mf = 0; mf < 4; mf++)
#pragma unroll
            for (int nf = 0; nf < 4; nf++)
                acc[mf][nf] = __builtin_amdgcn_mfma_f32_16x16x32_bf16(
                    af[mf], bfr[nf], acc[mf][nf], 0, 0, 0);
        __syncthreads();
    }

    const int rowbase = blockIdx.y * 128 + wm * 64;
    const int colbase = blockIdx.x * 128 + wn * 64;
#pragma unroll
    for (int nf = 0; nf < 4; nf++) {
        int col = colbase + nf * 16 + t16;
        float bv = (flags & GF_BIAS) ? bias[col] : 0.f;
#pragma unroll
        for (int mf = 0; mf < 4; mf++) {
            int row0 = rowbase + mf * 16 + q * 4;
#pragma unroll
            for (int r = 0; r < 4; r++) {
                float v = acc[mf][nf][r] + bv;
                if (flags & GF_RELU) v = fmaxf(v, 0.f);
                size_t row = (size_t)(row0 + r);
                if (flags & GF_OBF16) ((short*)Cout)[row * ldc + col] = f2bf(v);
                else                  ((float*)Cout)[row * ldc + col] = v;
            }
        }
    }
}

// ---------------- fused GAT scores + sparse aggregation (dir = blockIdx.y) ----------------
__global__ void agg_fused(const short* __restrict__ hpb2,
                          const float* __restrict__ as_p, const float* __restrict__ ad_p,
                          const float* __restrict__ as_f, const float* __restrict__ ad_f,
                          const int* __restrict__ mask, const int* __restrict__ logical,
                          const int* __restrict__ pol, const int* __restrict__ nvalid,
                          short* __restrict__ m, int dil) {
    int bl = blockIdx.x;
    int dir = blockIdx.y;
    int c = threadIdx.x;
    int b = bl >> 9;
    const float* a_s = dir ? as_f : as_p;
    const float* a_d = dir ? ad_f : ad_p;
    int mi = mask[bl];
    int li = logical[bl];
    int nv = nvalid[b];
    int js[3]; int nn = 0;
    if (mi) {
#pragma unroll
        for (int k = 1; k <= 3; k++) {
            int lj = dir ? (li - k * dil) : (li + k * dil);
            if (lj >= 0 && lj < nv) js[nn++] = pol[b * L_ + lj];
        }
    }
    int off0 = dir * 256 + c;
    float asv = a_s[c], adv = a_d[c];
    float vs = bf2f(hpb2[(size_t)bl * 512 + off0]);
    float vj[3];
    for (int k = 0; k < nn; k++) vj[k] = bf2f(hpb2[((size_t)(b * L_ + js[k])) * 512 + off0]);

    float ss = vs * asv, ds = vs * adv;
#pragma unroll
    for (int off = 32; off; off >>= 1) { ss += __shfl_xor(ss, off); ds += __shfl_xor(ds, off); }
    float dj[3];
    for (int k = 0; k < nn; k++) {
        float dv = vj[k] * adv;
#pragma unroll
        for (int off = 32; off; off >>= 1) dv += __shfl_xor(dv, off);
        dj[k] = dv;
    }
    float e0 = ss + ds; e0 = e0 > 0.f ? e0 : 0.2f * e0;
    float emax = e0, ev[3];
    for (int k = 0; k < nn; k++) {
        float e = ss + dj[k]; e = e > 0.f ? e : 0.2f * e;
        ev[k] = e; emax = fmaxf(emax, e);
    }
    float w0 = expf(e0 - emax), den = w0;
    float wv[3];
    for (int k = 0; k < nn; k++) { wv[k] = expf(ev[k] - emax); den += wv[k]; }
    float outv = w0 * vs;
    for (int k = 0; k < nn; k++) outv += wv[k] * vj[k];
    m[(size_t)bl * 512 + off0] = f2bf(outv / den);
}

// ---------------- GRU gates + LayerNorm + mask; G layout [rz(512)|inn(256)|hn(256)] ----------------
__global__ void gate_ln_kernel(const float* __restrict__ G,
                               float* __restrict__ h, short* __restrict__ hb,
                               const int* __restrict__ mask,
                               const float* __restrict__ lng, const float* __restrict__ lnb) {
    int bl = blockIdx.x;
    int c = threadIdx.x;
    __shared__ float red[8];
    size_t g0 = (size_t)bl * 1024;
    float r = sigmoidf_(G[g0 + c]);
    float z = sigmoidf_(G[g0 + 256 + c]);
    float n = tanhf(G[g0 + 512 + c] + r * G[g0 + 768 + c]);
    float hv = h[(size_t)bl * C_ + c];
    float hn2 = (1.f - z) * n + z * hv;

    int lane = c & 63, wave = c >> 6;
    float sum = hn2;
#pragma unroll
    for (int off = 32; off; off >>= 1) sum += __shfl_down(sum, off);
    if (lane == 0) red[wave] = sum;
    __syncthreads();
    float mu = (red[0] + red[1] + red[2] + red[3]) * (1.f / 256.f);
    float dv = hn2 - mu;
    float sq = dv * dv;
#pragma unroll
    for (int off = 32; off; off >>= 1) sq += __shfl_down(sq, off);
    __syncthreads();
    if (lane == 0) red[wave] = sq;
    __syncthreads();
    float var = (red[0] + red[1] + red[2] + red[3]) * (1.f / 256.f);
    float y = dv * rsqrtf(var + 1e-5f) * lng[c] + lnb[c];
    float outv = mask[bl] ? y : 0.f;
    h[(size_t)bl * C_ + c] = outv;
    hb[(size_t)bl * C_ + c] = f2bf(outv);
}

// ---------------- masked softmax pooling + both heads (1024 threads, l-parallel) ----------------
__global__ __launch_bounds__(1024) void pool_head_kernel(
    const float* __restrict__ h, const int* __restrict__ mask,
    const float* __restrict__ pw, const float* __restrict__ pb,
    const float* __restrict__ h0W, const float* __restrict__ h0b,
    const float* __restrict__ h1W, const float* __restrict__ h1b,
    float* __restrict__ out) {
    int b = blockIdx.x;
    int t = threadIdx.x;
    int lane = t & 63, wave = t >> 6;          // 16 waves
    __shared__ float sc[L_];
    __shared__ float red[20];
    __shared__ float part[4][C_];
    __shared__ float pooled[C_];

    // phase 1: scores, 16 waves x 32 rows
    float4 wv = *(const float4*)&pw[lane * 4];
    for (int l = wave; l < L_; l += 16) {
        float4 hv = *(const float4*)&h[((size_t)b * L_ + l) * C_ + lane * 4];
        float p = hv.x * wv.x + hv.y * wv.y + hv.z * wv.z + hv.w * wv.w;
#pragma unroll
        for (int off = 32; off; off >>= 1) p += __shfl_down(p, off);
        if (lane == 0) sc[l] = mask[b * L_ + l] ? (p + pb[0]) : NEGV;
    }
    __syncthreads();

    // phase 2: softmax over 512 (threads t<512 active)
    float v = (t < L_) ? sc[t] : NEGV;
    float mx = v;
#pragma unroll
    for (int off = 32; off; off >>= 1) mx = fmaxf(mx, __shfl_down(mx, off));
    if (lane == 0) red[wave] = mx;
    __syncthreads();
    if (t == 0) {
        float g = red[0];
        for (int i = 1; i < 16; i++) g = fmaxf(g, red[i]);
        red[16] = g;
    }
    __syncthreads();
    float gmax = red[16];
    float e = (t < L_) ? expf(v - gmax) : 0.f;
    float ssum = e;
#pragma unroll
    for (int off = 32; off; off >>= 1) ssum += __shfl_down(ssum, off);
    if (lane == 0) red[wave] = ssum;
    __syncthreads();
    if (t == 0) {
        float g = 0.f;
        for (int i = 0; i < 16; i++) g += red[i];
        red[17] = 1.f / g;
    }
    __syncthreads();
    if (t < L_) sc[t] = e * red[17];
    __syncthreads();

    // phase 3: pooled[c] = sum_l sc[l]*h[l][c], l split over 4 groups
    int g = t >> 8, c = t & 255;
    const float* hrow = &h[((size_t)b * L_ + g * 128) * C_ + c];
    const float* scg = &sc[g * 128];
    float a0 = 0.f, a1 = 0.f, a2 = 0.f, a3 = 0.f;
    for (int l = 0; l < 128; l += 4) {
        a0 = fmaf(scg[l + 0], hrow[(size_t)(l + 0) * C_], a0);
        a1 = fmaf(scg[l + 1], hrow[(size_t)(l + 1) * C_], a1);
        a2 = fmaf(scg[l + 2], hrow[(size_t)(l + 2) * C_], a2);
        a3 = fmaf(scg[l + 3], hrow[(size_t)(l + 3) * C_], a3);
    }
    part[g][c] = (a0 + a1) + (a2 + a3);
    __syncthreads();
    if (t < C_) pooled[t] = (part[0][t] + part[1][t]) + (part[2][t] + part[3][t]);
    __syncthreads();

    // phase 4: heads, one output per wave slot
    for (int o = wave; o < 70; o += 16) {
        const float* W = (o < 50) ? (h0W + (size_t)o * C_) : (h1W + (size_t)(o - 50) * C_);
        float bb = (o < 50) ? h0b[o] : h1b[o - 50];
        float4 w4 = *(const float4*)&W[lane * 4];
        float4 p4 = *(const float4*)&pooled[lane * 4];
        float s = p4.x * w4.x + p4.y * w4.y + p4.z * w4.z + p4.w * w4.w;
#pragma unroll
        for (int off = 32; off; off >>= 1) s += __shfl_down(s, off);
        if (lane == 0) out[b * 70 + o] = s + bb;
    }
}

extern "C" void kernel_launch(void* const* d_in, const int* in_sizes, int n_in,
                              void* d_out, int out_size, void* d_ws, size_t ws_size,
                              hipStream_t stream) {
    const int*   x    = (const int*)d_in[0];
    const float* emb  = (const float*)d_in[1];
    const float* pos  = (const float*)d_in[2];
    const float* gpW  = (const float*)d_in[3];
    const float* gpas = (const float*)d_in[4];
    const float* gpad = (const float*)d_in[5];
    const float* gfW  = (const float*)d_in[6];
    const float* gfas = (const float*)d_in[7];
    const float* gfad = (const float*)d_in[8];
    const float* msgW = (const float*)d_in[9];
    const float* msgb = (const float*)d_in[10];
    const float* Wih  = (const float*)d_in[11];
    const float* bih  = (const float*)d_in[12];
    const float* Whh  = (const float*)d_in[13];
    const float* bhh  = (const float*)d_in[14];
    const float* lng  = (const float*)d_in[15];
    const float* lnb  = (const float*)d_in[16];
    const float* pw   = (const float*)d_in[17];
    const float* pb   = (const float*)d_in[18];
    const float* h0W  = (const float*)d_in[19];
    const float* h0b  = (const float*)d_in[20];
    const float* h1W  = (const float*)d_in[21];
    const float* h1b  = (const float*)d_in[22];
    float* out = (float*)d_out;

    // Workspace layout, units MW = 1Mi floats = 4 MiB. Sizes (corrected!):
    //   h    fp32 [32768, 256] =  8 MW   -> [ 0,  8)
    //   hb   bf16 [32768, 256] =  4 MW   -> [ 8, 12)
    //   mmb  bf16 [32768, 256] =  4 MW   -> [12, 16)
    //   G    fp32 [32768,1024] = 32 MW   -> [16, 48)
    //   hpb2 bf16 [32768, 512] =  8 MW   -> [16, 24)  (inside G; dead before G written)
    //   mb   bf16 [32768, 512] =  8 MW   -> [24, 32)  (inside G; dead before G written)
    //   weights/bias/masks               -> [48, ~49.3)   total ~198 MiB
    // Per-layer dataflow: proj(hb->hpb2); agg(hpb2->mb); msg(mb->mmb);
    // gru(mmb,hb->G); gate_ln(G,h->h,hb).  All step read/write sets disjoint.
    const size_t MW = 1024 * 1024;
    float* ws = (float*)d_ws;
    float* h    = ws;
    short* hb   = (short*)(ws + 8 * MW);
    short* mmb  = (short*)(ws + 12 * MW);
    float* G    = ws + 16 * MW;
    short* hpb2 = (short*)(ws + 16 * MW);
    short* mb   = (short*)(ws + 24 * MW);
    short* W2cat = (short*)(ws + 48 * MW);              // 3*512*256  shorts
    short* msgWb = W2cat + 3 * 512 * 256;               // 3*256*512  shorts
    short* Bcat  = msgWb + 3 * 256 * 512;               // 3*1024*512 shorts
    float* bias_cat = (float*)(Bcat + 3 * 1024 * 512);  // 3*1024 floats
    int* mask    = (int*)(bias_cat + 3 * 1024);
    int* logical = mask + B_ * L_;
    int* pol     = logical + B_ * L_;
    int* nvalid  = pol + B_ * L_;

    // weight prep
    prep_w2<<<(3 * 512 * 256 + 255) / 256, 256, 0, stream>>>(gpW, gfW, W2cat);
    f2bf_kernel<<<(3 * 256 * 512 + 255) / 256, 256, 0, stream>>>(msgW, msgWb, 3 * 256 * 512);
    prep_gru<<<(3 * 1024 * 512 + 255) / 256, 256, 0, stream>>>(Wih, Whh, Bcat);
    prep_bias<<<12, 256, 0, stream>>>(bih, bhh, bias_cat);

    scan_kernel<<<B_, L_, 0, stream>>>(x, mask, logical, pol, nvalid);
    embed_kernel<<<B_ * L_ / 4, 256, 0, stream>>>(x, emb, pos, h, hb);

    const int DILS[LAY] = {1, 2, 4};

    for (int l = 0; l < LAY; l++) {
        int dil = DILS[l];
        // hpb2 = hb @ [gpW;gfW]^T   (N=512, bf16 out)
        bgemm<<<dim3(4, 256), 256, 0, stream>>>(hb, nullptr, W2cat + (size_t)l * 512 * 256,
                                                hpb2, nullptr, 256, 256, 512, GF_OBF16);
        // sparse GAT aggregation, both directions
        agg_fused<<<dim3(B_ * L_, 2), 256, 0, stream>>>(hpb2,
            gpas + l * C_, gpad + l * C_, gfas + l * C_, gfad + l * C_,
            mask, logical, pol, nvalid, mb, dil);
        // mm = relu(m @ msgW^T + msgb) -> bf16
        bgemm<<<dim3(2, 256), 256, 0, stream>>>(mb, nullptr, msgWb + (size_t)l * 256 * 512,
                                                mmb, msgb + l * C_, 512, 512, 256,
                                                GF_BIAS | GF_RELU | GF_OBF16);
        // G = [mm|h] @ Bcat^T + bias_cat   (N=1024, fp32 out)
        bgemm<<<dim3(8, 256), 256, 0, stream>>>(mmb, hb, Bcat + (size_t)l * 1024 * 512,
                                                G, bias_cat + l * 1024, 512, 256, 1024,
                                                GF_BIAS);
        gate_ln_kernel<<<B_ * L_, 256, 0, stream>>>(G, h, hb, mask,
                                                    lng + l * C_, lnb + l * C_);
    }

    pool_head_kernel<<<B_, 1024, 0, stream>>>(h, mask, pw, pb, h0W, h0b, h1W, h1b, out);
}